// Round 8
// baseline (4715.638 us; speedup 1.0000x reference)
//
// LSTM Seq2Seq persistent kernel, round 8: paired-recurrence pipelining.
// Two independent batch groups per WG-set; group A's exchange latency hides
// under group B's compute, and vice versa.
//
//  - 256 WGs x 256 thr, 1 WG/CU (LDS ~108KB). 8 pairs x 32 WGs.
//    pair = wg>>5, jm = wg&31. Group A rows = 32*pair..+16, B = +16..+32.
//  - WG owns 32 fm cols for BOTH groups: per n-tile n (0,1), lane lr:
//    col = (2n + (lr>>3))*256 + 8*jm + (lr&7). h-slice owned: cols [8jm,8jm+8).
//  - Weights (shared across batch!): B-frags f16 hi/lo in VGPRs: Bh/Bl[3][2]
//    (48 VGPRs). Wave wv owns k-tiles {wv, wv+4, wv+8}.
//  - fm = Ah*Bh + Ah*Bl + Al*Bh (fp32-grade), partials via fm_p, gates
//    elementwise (A on thr<128, B on thr>=128; c in registers).
//  - h published as packed u32 (hi f16 | lo f16) with sc0 sc1; consumers
//    unpack with bit-ops straight into A LDS. Atomic-counter barrier per
//    group (32 arrivals), single poller + s_sleep - the round-3 proven one.
//  - Decoder: paired too; z computed A/B concurrently, LN split by half,
//    one combined arrive for the z phase.

#include <hip/hip_runtime.h>
#include <cmath>

typedef _Float16 f16;
typedef _Float16 f16x8v __attribute__((ext_vector_type(8)));
typedef float f32x4v __attribute__((ext_vector_type(4)));

#define NTHR 256
#define WPP  32   // WGs per pair (barrier width per group)

__device__ __forceinline__ float sigmoidf_(float x) { return 1.0f / (1.0f + expf(-x)); }

__device__ __forceinline__ void st_sc_u(unsigned* p, unsigned v) {
  asm volatile("global_store_dword %0, %1, off sc0 sc1" :: "v"(p), "v"(v) : "memory");
}
__device__ __forceinline__ void st_sc_f(float* p, float v) {
  asm volatile("global_store_dword %0, %1, off sc0 sc1" :: "v"(p), "v"(v) : "memory");
}

// 4 coherent 16B loads, 4KB apart, single drain.
__device__ __forceinline__ void ld4u_sc(const unsigned* p, uint4& a, uint4& b,
                                        uint4& c, uint4& d) {
  asm volatile(
      "global_load_dwordx4 %0, %4, off sc0 sc1\n\t"
      "global_load_dwordx4 %1, %5, off sc0 sc1\n\t"
      "global_load_dwordx4 %2, %6, off sc0 sc1\n\t"
      "global_load_dwordx4 %3, %7, off sc0 sc1\n\t"
      "s_waitcnt vmcnt(0)"
      : "=&v"(a), "=&v"(b), "=&v"(c), "=&v"(d)
      : "v"(p), "v"(p + 1024), "v"(p + 2048), "v"(p + 3072) : "memory");
}
__device__ __forceinline__ void ld4f_sc(const float* p, float4& a, float4& b,
                                        float4& c, float4& d) {
  asm volatile(
      "global_load_dwordx4 %0, %4, off sc0 sc1\n\t"
      "global_load_dwordx4 %1, %5, off sc0 sc1\n\t"
      "global_load_dwordx4 %2, %6, off sc0 sc1\n\t"
      "global_load_dwordx4 %3, %7, off sc0 sc1\n\t"
      "s_waitcnt vmcnt(0)"
      : "=&v"(a), "=&v"(b), "=&v"(c), "=&v"(d)
      : "v"(p), "v"(p + 1024), "v"(p + 2048), "v"(p + 3072) : "memory");
}

__device__ __forceinline__ void arrive_bar(unsigned* cg) {
  asm volatile("s_waitcnt vmcnt(0)" ::: "memory");   // drain sc1 stores to L3
  __syncthreads();
  if (threadIdx.x == 0)
    (void)__hip_atomic_fetch_add(cg, 1u, __ATOMIC_RELAXED, __HIP_MEMORY_SCOPE_AGENT);
}
__device__ __forceinline__ void wait_bar(unsigned* cg, unsigned target) {
  if (threadIdx.x == 0) {
    unsigned guard = 0;
    while (__hip_atomic_load(cg, __ATOMIC_RELAXED, __HIP_MEMORY_SCOPE_AGENT) < target) {
      __builtin_amdgcn_s_sleep(1);
      if (++guard > (1u << 22)) break;   // safety valve
    }
  }
  __syncthreads();
}

__device__ __forceinline__ unsigned packhl(float v) {
  f16 h = (f16)v;
  f16 lo = (f16)(v - (float)h);
  unsigned short hb, lb;
  __builtin_memcpy(&hb, &h, 2); __builtin_memcpy(&lb, &lo, 2);
  return (unsigned)hb | ((unsigned)lb << 16);
}
__device__ __forceinline__ float unpackf(unsigned u) {
  unsigned short hb = (unsigned short)(u & 0xffffu), lb = (unsigned short)(u >> 16);
  f16 h, l;
  __builtin_memcpy(&h, &hb, 2); __builtin_memcpy(&l, &lb, 2);
  return (float)h + (float)l;
}
// 4 packed u32 -> 4 hi f16 + 4 lo f16 (8B each), pure bit ops.
__device__ __forceinline__ void unpack_wr(uint4 c, f16* ph, f16* pl) {
  unsigned h01 = (c.x & 0xffffu) | (c.y << 16);
  unsigned h23 = (c.z & 0xffffu) | (c.w << 16);
  unsigned l01 = (c.x >> 16) | (c.y & 0xffff0000u);
  unsigned l23 = (c.z >> 16) | (c.w & 0xffff0000u);
  uint2 hh = {h01, h23}, ll = {l01, l23};
  *(uint2*)ph = hh; *(uint2*)pl = ll;
}

__device__ __forceinline__ void conv8_wr(float4 a, float4 b, f16* ph, f16* pl) {
  f16x8v h, l;
  h[0]=(f16)a.x; h[1]=(f16)a.y; h[2]=(f16)a.z; h[3]=(f16)a.w;
  h[4]=(f16)b.x; h[5]=(f16)b.y; h[6]=(f16)b.z; h[7]=(f16)b.w;
  l[0]=(f16)(a.x-(float)h[0]); l[1]=(f16)(a.y-(float)h[1]);
  l[2]=(f16)(a.z-(float)h[2]); l[3]=(f16)(a.w-(float)h[3]);
  l[4]=(f16)(b.x-(float)h[4]); l[5]=(f16)(b.y-(float)h[5]);
  l[6]=(f16)(b.z-(float)h[6]); l[7]=(f16)(b.w-(float)h[7]);
  *(f16x8v*)ph = h; *(f16x8v*)pl = l;
}

__global__ __launch_bounds__(NTHR, 1) void lstm_k(
    const float* __restrict__ X,  const float* __restrict__ Wx,
    const float* __restrict__ Wh, const float* __restrict__ Bg,
    const float* __restrict__ W1, const float* __restrict__ B1,
    const float* __restrict__ LNG, const float* __restrict__ LNB,
    const float* __restrict__ W2, const float* __restrict__ B2,
    float* __restrict__ Y, unsigned* __restrict__ CNT,
    unsigned* __restrict__ HBu, float* __restrict__ ZB)
{
  // LDS ~108.5KB (1 WG/CU)
  __shared__ f16   A_hi[2][16][392];   // [group][row][k: 0..127 x, 128..383 h]
  __shared__ f16   A_lo[2][16][392];
  __shared__ float fm_p[4][2][16][20]; // [wave][n-tile][lr][row+pad]
  __shared__ float hst[2][16][260];    // decoder f32 staging per group
  __shared__ float w1_lds[8][260];     // W1 slice transposed [c8][k]
  __shared__ float w2_lds[4][260];     // W2 slice transposed [yc][k]
  __shared__ float lng_lds[256], lnb_lds[256];
  __shared__ float ln_mu[2][16], ln_rs[2][16];

  const int tid  = threadIdx.x;
  const int wg   = blockIdx.x;
  const int pair = wg >> 5;
  const int jm   = wg & 31;
  const int n0A  = pair * 32;
  const int n0B  = n0A + 16;
  unsigned* cgA  = CNT + (2 * pair)     * 32;   // 128B-spaced counters
  unsigned* cgB  = CNT + (2 * pair + 1) * 32;

  const int l  = tid & 63;
  const int wv = __builtin_amdgcn_readfirstlane(tid >> 6);
  const int lr = l & 15;            // B-frag col / A-frag row / C col
  const int ko = (l >> 4) * 8;      // k octet within 32-k tile

  // ---- B fragments (SHARED by both groups): wave wv owns kt {wv,wv+4,wv+8} ----
  f16x8v Bh[3][2], Bl[3][2];
  #pragma unroll
  for (int ki = 0; ki < 3; ++ki) {
    const int kt = wv + 4 * ki;
    #pragma unroll
    for (int n = 0; n < 2; ++n) {
      const int gq  = 2 * n + (lr >> 3);
      const int col = gq * 256 + 8 * jm + (lr & 7);
      #pragma unroll
      for (int j = 0; j < 8; ++j) {
        int k = kt * 32 + ko + j;
        float v = (k < 128) ? Wx[k * 1024 + col] : Wh[(k - 128) * 1024 + col];
        f16 hi = (f16)v;
        Bh[ki][n][j] = hi;
        Bl[ki][n][j] = (f16)(v - (float)hi);
      }
    }
  }

  // ---- head weights / LN params ----
  for (int idx = tid; idx < 256 * 8; idx += NTHR) {
    int k = idx >> 3, c = idx & 7;
    w1_lds[c][k] = W1[k * 256 + 8 * jm + c];
  }
  for (int idx = tid; idx < 256 * 4; idx += NTHR) {
    int k = idx >> 2, c = idx & 3;
    w2_lds[c][k] = W2[k * 128 + 4 * jm + c];
  }
  lng_lds[tid] = LNG[tid];
  lnb_lds[tid] = LNB[tid];

  // gate roles: threads<128 -> group A, >=128 -> group B. Same column slice.
  const int r_g = (tid & 127) >> 3;   // row 0..15
  const int c8  = tid & 7;            // owned h col within slice
  const float bias0 = Bg[        8 * jm + c8];
  const float bias1 = Bg[256   + 8 * jm + c8];
  const float bias2 = Bg[512   + 8 * jm + c8];
  const float bias3 = Bg[768   + 8 * jm + c8];
  const float b1reg = B1[8 * jm + c8];
  const float b2reg = B2[4 * jm + (tid & 3)];
  float c_reg = 0.0f;   // cell state for this thread's (group, row, col)

  // ---- prologue: zero h-regions, stage x(0) for both groups ----
  {
    const int row = tid >> 4, cb = (tid & 15) * 16;
    f16x8v z8 = {0,0,0,0,0,0,0,0};
    #pragma unroll
    for (int g2 = 0; g2 < 2; ++g2) {
      *(f16x8v*)&A_hi[g2][row][128 + cb]     = z8;
      *(f16x8v*)&A_hi[g2][row][128 + cb + 8] = z8;
      *(f16x8v*)&A_lo[g2][row][128 + cb]     = z8;
      *(f16x8v*)&A_lo[g2][row][128 + cb + 8] = z8;
    }
    const float* xpA = X + (size_t)(n0A + row) * 131072 + (size_t)(tid & 15) * 8;
    conv8_wr(*(const float4*)xpA, *(const float4*)(xpA + 4),
             &A_hi[0][row][(tid & 15) * 8], &A_lo[0][row][(tid & 15) * 8]);
    const float* xpB = xpA + (size_t)16 * 131072;
    conv8_wr(*(const float4*)xpB, *(const float4*)(xpB + 4),
             &A_hi[1][row][(tid & 15) * 8], &A_lo[1][row][(tid & 15) * 8]);
  }
  __syncthreads();

  // stage packed h (16 rows x 256) into group g's A h-region
  auto stage_h = [&](const unsigned* base, int g2) {
    uint4 c0, c1, c2, c3;
    ld4u_sc(base + tid * 4, c0, c1, c2, c3);   // chunk j: row 4j+(tid>>6)
    const int r0 = tid >> 6, cb = (tid & 63) * 4;
    unpack_wr(c0, &A_hi[g2][r0     ][128 + cb], &A_lo[g2][r0     ][128 + cb]);
    unpack_wr(c1, &A_hi[g2][r0 + 4 ][128 + cb], &A_lo[g2][r0 + 4 ][128 + cb]);
    unpack_wr(c2, &A_hi[g2][r0 + 8 ][128 + cb], &A_lo[g2][r0 + 8 ][128 + cb]);
    unpack_wr(c3, &A_hi[g2][r0 + 12][128 + cb], &A_lo[g2][r0 + 12][128 + cb]);
  };
  auto stage_h_hst = [&](const unsigned* base, int g2) {  // + f32 into hst
    uint4 c0, c1, c2, c3;
    ld4u_sc(base + tid * 4, c0, c1, c2, c3);
    const int r0 = tid >> 6, cb = (tid & 63) * 4;
    unpack_wr(c0, &A_hi[g2][r0     ][128 + cb], &A_lo[g2][r0     ][128 + cb]);
    unpack_wr(c1, &A_hi[g2][r0 + 4 ][128 + cb], &A_lo[g2][r0 + 4 ][128 + cb]);
    unpack_wr(c2, &A_hi[g2][r0 + 8 ][128 + cb], &A_lo[g2][r0 + 8 ][128 + cb]);
    unpack_wr(c3, &A_hi[g2][r0 + 12][128 + cb], &A_lo[g2][r0 + 12][128 + cb]);
    float4 f0 = {unpackf(c0.x), unpackf(c0.y), unpackf(c0.z), unpackf(c0.w)};
    float4 f1 = {unpackf(c1.x), unpackf(c1.y), unpackf(c1.z), unpackf(c1.w)};
    float4 f2 = {unpackf(c2.x), unpackf(c2.y), unpackf(c2.z), unpackf(c2.w)};
    float4 f3 = {unpackf(c3.x), unpackf(c3.y), unpackf(c3.z), unpackf(c3.w)};
    *(float4*)&hst[g2][r0     ][cb] = f0;
    *(float4*)&hst[g2][r0 + 4 ][cb] = f1;
    *(float4*)&hst[g2][r0 + 8 ][cb] = f2;
    *(float4*)&hst[g2][r0 + 12][cb] = f3;
  };

  // fm for group g2: encoder (with x) or decoder (h only)
  auto fm_compute = [&](int g2, bool with_x) {
    f32x4v a0[2], a1[2], a2[2];
    #pragma unroll
    for (int n = 0; n < 2; ++n) { a0[n] = {0,0,0,0}; a1[n] = {0,0,0,0}; a2[n] = {0,0,0,0}; }
    f16x8v ah1 = *(const f16x8v*)&A_hi[g2][lr][128 + wv * 32 + ko];
    f16x8v al1 = *(const f16x8v*)&A_lo[g2][lr][128 + wv * 32 + ko];
    f16x8v ah2 = *(const f16x8v*)&A_hi[g2][lr][128 + (wv + 4) * 32 + ko];
    f16x8v al2 = *(const f16x8v*)&A_lo[g2][lr][128 + (wv + 4) * 32 + ko];
    if (with_x) {
      f16x8v axh = *(const f16x8v*)&A_hi[g2][lr][wv * 32 + ko];
      f16x8v axl = *(const f16x8v*)&A_lo[g2][lr][wv * 32 + ko];
      #pragma unroll
      for (int n = 0; n < 2; ++n) {
        a0[n] = __builtin_amdgcn_mfma_f32_16x16x32_f16(axh, Bh[0][n], a0[n], 0, 0, 0);
        a1[n] = __builtin_amdgcn_mfma_f32_16x16x32_f16(axh, Bl[0][n], a1[n], 0, 0, 0);
        a2[n] = __builtin_amdgcn_mfma_f32_16x16x32_f16(axl, Bh[0][n], a2[n], 0, 0, 0);
      }
    }
    #pragma unroll
    for (int n = 0; n < 2; ++n) {
      a0[n] = __builtin_amdgcn_mfma_f32_16x16x32_f16(ah1, Bh[1][n], a0[n], 0, 0, 0);
      a1[n] = __builtin_amdgcn_mfma_f32_16x16x32_f16(ah1, Bl[1][n], a1[n], 0, 0, 0);
      a2[n] = __builtin_amdgcn_mfma_f32_16x16x32_f16(al1, Bh[1][n], a2[n], 0, 0, 0);
      a0[n] = __builtin_amdgcn_mfma_f32_16x16x32_f16(ah2, Bh[2][n], a0[n], 0, 0, 0);
      a1[n] = __builtin_amdgcn_mfma_f32_16x16x32_f16(ah2, Bl[2][n], a1[n], 0, 0, 0);
      a2[n] = __builtin_amdgcn_mfma_f32_16x16x32_f16(al2, Bh[2][n], a2[n], 0, 0, 0);
    }
    #pragma unroll
    for (int n = 0; n < 2; ++n) {
      f32x4v sm = a0[n] + a1[n] + a2[n];
      *(f32x4v*)&fm_p[wv][n][lr][(l >> 4) * 4] = sm;
    }
  };

  // gate partial reduce (callers add bias / activations)
  auto reduce4 = [&](float& fi, float& ff, float& fo, float& fg) {
    fi = bias0; ff = bias1; fo = bias2; fg = bias3;
    #pragma unroll
    for (int ww = 0; ww < 4; ++ww) {
      fi += fm_p[ww][0][c8][r_g];
      ff += fm_p[ww][0][8 + c8][r_g];
      fo += fm_p[ww][1][c8][r_g];
      fg += fm_p[ww][1][8 + c8][r_g];
    }
  };

  const size_t HBUF = 65536;   // u32 elems per h buffer

  // ================= ENCODER (t = 0..1023) =================
  for (int t = 0; t < 1024; ++t) {
    float4 xaA, xbA, xaB, xbB;
    if (t < 1023) {  // prefetch x(t+1) both groups (plain cached loads)
      const float* xpA = X + (size_t)(n0A + (tid >> 4)) * 131072
                           + (size_t)(t + 1) * 128 + (size_t)(tid & 15) * 8;
      xaA = *(const float4*)xpA; xbA = *(const float4*)(xpA + 4);
      const float* xpB = xpA + (size_t)16 * 131072;
      xaB = *(const float4*)xpB; xbB = *(const float4*)(xpB + 4);
    }

    // ---- group A step ----
    fm_compute(0, true);
    __syncthreads();
    if (tid < 128) {   // waves 0,1: gates A
      float fi, ff, fo, fg; reduce4(fi, ff, fo, fg);
      float si = sigmoidf_(fi), sf = sigmoidf_(ff), so = sigmoidf_(fo);
      float tg = tanhf(fg);
      c_reg = c_reg * sf + si * tg;
      float hv = so * tanhf(c_reg);
      st_sc_u(HBu + (size_t)(t & 1) * HBUF + (size_t)(n0A + r_g) * 256 + 8 * jm + c8,
              packhl(hv));
    }
    if (t < 1023)     // all threads (waves 2,3 arrive here early - overlap)
      conv8_wr(xaA, xbA, &A_hi[0][tid >> 4][(tid & 15) * 8],
                         &A_lo[0][tid >> 4][(tid & 15) * 8]);
    arrive_bar(cgA);

    // ---- group B step (hides A's exchange latency) ----
    fm_compute(1, true);
    __syncthreads();
    if (tid >= 128) {  // waves 2,3: gates B
      float fi, ff, fo, fg; reduce4(fi, ff, fo, fg);
      float si = sigmoidf_(fi), sf = sigmoidf_(ff), so = sigmoidf_(fo);
      float tg = tanhf(fg);
      c_reg = c_reg * sf + si * tg;
      float hv = so * tanhf(c_reg);
      st_sc_u(HBu + (size_t)(t & 1) * HBUF + (size_t)(n0B + r_g) * 256 + 8 * jm + c8,
              packhl(hv));
    }
    if (t < 1023)
      conv8_wr(xaB, xbB, &A_hi[1][tid >> 4][(tid & 15) * 8],
                         &A_lo[1][tid >> 4][(tid & 15) * 8]);
    arrive_bar(cgB);

    if (t < 1023) {
      wait_bar(cgA, (unsigned)(WPP * (t + 1)));
      stage_h(HBu + (size_t)(t & 1) * HBUF + (size_t)n0A * 256, 0);
      wait_bar(cgB, (unsigned)(WPP * (t + 1)));
      stage_h(HBu + (size_t)(t & 1) * HBUF + (size_t)n0B * 256, 1);
      __syncthreads();
    }
  }

  // ---- decoder prologue: stage h(1023) (buffer parity 1) ----
  wait_bar(cgA, (unsigned)(WPP * 1024));
  stage_h(HBu + HBUF + (size_t)n0A * 256, 0);
  wait_bar(cgB, (unsigned)(WPP * 1024));
  stage_h(HBu + HBUF + (size_t)n0B * 256, 1);
  __syncthreads();
  unsigned arr = 1024;

  // ================= DECODER (s = 0..31) =================
  for (int s = 0; s < 32; ++s) {
    const int t = 1024 + s;

    fm_compute(0, false);
    __syncthreads();
    if (tid < 128) {   // RAW gates A
      float fi, ff, fo, fg; reduce4(fi, ff, fo, fg);
      c_reg = c_reg * ff + fi * fg;
      float hv = fo * tanhf(c_reg);
      st_sc_u(HBu + (size_t)(t & 1) * HBUF + (size_t)(n0A + r_g) * 256 + 8 * jm + c8,
              packhl(hv));
    }
    arrive_bar(cgA);

    fm_compute(1, false);
    __syncthreads();
    if (tid >= 128) {  // RAW gates B
      float fi, ff, fo, fg; reduce4(fi, ff, fo, fg);
      c_reg = c_reg * ff + fi * fg;
      float hv = fo * tanhf(c_reg);
      st_sc_u(HBu + (size_t)(t & 1) * HBUF + (size_t)(n0B + r_g) * 256 + 8 * jm + c8,
              packhl(hv));
    }
    arrive_bar(cgB);
    ++arr;

    wait_bar(cgA, WPP * arr);
    stage_h_hst(HBu + (size_t)(t & 1) * HBUF + (size_t)n0A * 256, 0);
    wait_bar(cgB, WPP * arr);
    stage_h_hst(HBu + (size_t)(t & 1) * HBUF + (size_t)n0B * 256, 1);
    __syncthreads();

    {  // z = h @ W1 + b1 : A on thr<128, B on thr>=128, concurrent
      const int g2 = tid >> 7;
      float za = b1reg;
      const float* hr = &hst[g2][r_g][0];
      const float* wr = &w1_lds[c8][0];
      #pragma unroll 4
      for (int kc = 0; kc < 64; ++kc) {
        float4 h4 = *(const float4*)(hr + kc * 4);
        float4 w4 = *(const float4*)(wr + kc * 4);
        za = fmaf(h4.x, w4.x, fmaf(h4.y, w4.y, fmaf(h4.z, w4.z, fmaf(h4.w, w4.w, za))));
      }
      st_sc_f(ZB + (size_t)(n0A + g2 * 16 + r_g) * 256 + 8 * jm + c8, za);
    }
    asm volatile("s_waitcnt vmcnt(0)" ::: "memory");
    __syncthreads();
    if (tid == 0) {   // combined arrive for both groups
      (void)__hip_atomic_fetch_add(cgA, 1u, __ATOMIC_RELAXED, __HIP_MEMORY_SCOPE_AGENT);
      (void)__hip_atomic_fetch_add(cgB, 1u, __ATOMIC_RELAXED, __HIP_MEMORY_SCOPE_AGENT);
    }
    ++arr;

    wait_bar(cgA, WPP * arr);
    {  // stage zA -> hst[0]
      float4 a, b, c, d;
      ld4f_sc(ZB + (size_t)n0A * 256 + tid * 4, a, b, c, d);
      const int r0 = tid >> 6, cb = (tid & 63) * 4;
      *(float4*)&hst[0][r0][cb] = a;      *(float4*)&hst[0][r0 + 4][cb] = b;
      *(float4*)&hst[0][r0 + 8][cb] = c;  *(float4*)&hst[0][r0 + 12][cb] = d;
    }
    wait_bar(cgB, WPP * arr);
    {  // stage zB -> hst[1]
      float4 a, b, c, d;
      ld4f_sc(ZB + (size_t)n0B * 256 + tid * 4, a, b, c, d);
      const int r0 = tid >> 6, cb = (tid & 63) * 4;
      *(float4*)&hst[1][r0][cb] = a;      *(float4*)&hst[1][r0 + 4][cb] = b;
      *(float4*)&hst[1][r0 + 8][cb] = c;  *(float4*)&hst[1][r0 + 12][cb] = d;
    }
    __syncthreads();

    {  // LayerNorm stats: thr<128 group A, thr>=128 group B
      const int g2 = tid >> 7;
      const int l8 = tid & 7;
      const float* zr = &hst[g2][r_g][0];
      float s1 = 0.f, s2 = 0.f;
      #pragma unroll
      for (int k = 0; k < 8; ++k) {   // interleaved cols: bank-spread
        float4 v = *(const float4*)(zr + l8 * 4 + k * 32);
        s1 += v.x + v.y + v.z + v.w;
        s2 += v.x*v.x + v.y*v.y + v.z*v.z + v.w*v.w;
      }
      #pragma unroll
      for (int d = 1; d < 8; d <<= 1) { s1 += __shfl_xor(s1, d); s2 += __shfl_xor(s2, d); }
      float mu = s1 * (1.0f / 256.0f);
      float var = s2 * (1.0f / 256.0f) - mu * mu;
      float rstd = rsqrtf(var + 1e-5f);
      if (l8 == 0) { ln_mu[g2][r_g] = mu; ln_rs[g2][r_g] = rstd; }
    }
    __syncthreads();

    #pragma unroll
    for (int rep = 0; rep < 8; ++rep) {  // normalize + affine + relu (both groups)
      int idx = tid + 256 * rep;         // 2048 float4 total: [g][16][64]
      int g2 = idx >> 10, r = (idx >> 6) & 15, q = idx & 63;
      float mu = ln_mu[g2][r], rs = ln_rs[g2][r];
      float4 v = *(float4*)&hst[g2][r][q * 4];
      int cb = q * 4;
      v.x = fmaxf(fmaf((v.x - mu) * rs, lng_lds[cb    ], lnb_lds[cb    ]), 0.f);
      v.y = fmaxf(fmaf((v.y - mu) * rs, lng_lds[cb + 1], lnb_lds[cb + 1]), 0.f);
      v.z = fmaxf(fmaf((v.z - mu) * rs, lng_lds[cb + 2], lnb_lds[cb + 2]), 0.f);
      v.w = fmaxf(fmaf((v.w - mu) * rs, lng_lds[cb + 3], lnb_lds[cb + 3]), 0.f);
      *(float4*)&hst[g2][r][q * 4] = v;
    }
    __syncthreads();

    if ((tid & 127) < 64) {  // y: thr 0..63 -> A, 128..191 -> B
      const int g2 = tid >> 7;
      const int r = (tid & 63) >> 2, yc = tid & 3;
      float ya = b2reg;
      const float* zr = &hst[g2][r][0];
      const float* wr = &w2_lds[yc][0];
      #pragma unroll 4
      for (int kc = 0; kc < 64; ++kc) {
        float4 z4 = *(const float4*)(zr + kc * 4);
        float4 w4 = *(const float4*)(wr + kc * 4);
        ya = fmaf(z4.x, w4.x, fmaf(z4.y, w4.y, fmaf(z4.z, w4.z, fmaf(z4.w, w4.w, ya))));
      }
      Y[(size_t)(n0A + g2 * 16 + r) * 4096 + (size_t)s * 128 + 4 * jm + yc] = ya;
    }
    __syncthreads();   // hst safe before next iteration's staging
  }
}

extern "C" void kernel_launch(void* const* d_in, const int* in_sizes, int n_in,
                              void* d_out, int out_size, void* d_ws, size_t ws_size,
                              hipStream_t stream) {
  const float* X   = (const float*)d_in[0];
  const float* Wx  = (const float*)d_in[1];
  const float* Wh  = (const float*)d_in[2];
  const float* b   = (const float*)d_in[3];
  const float* W1  = (const float*)d_in[4];
  const float* b1  = (const float*)d_in[5];
  const float* lng = (const float*)d_in[6];
  const float* lnb = (const float*)d_in[7];
  const float* W2  = (const float*)d_in[8];
  const float* b2  = (const float*)d_in[9];
  float* Y = (float*)d_out;

  // ws layout (bytes):
  //  [0,2048)          CNT  per-group counters (16 groups x 128B)
  //  [4096, +512KB)    HBu  packed h double buffer [2][256][256] u32
  //  then 256KB        ZB   z buffer [256][256] f32
  unsigned* CNTp = (unsigned*)d_ws;
  unsigned* HBu  = (unsigned*)((char*)d_ws + 4096);
  float*    ZB   = (float*)((char*)d_ws + 4096 + 524288);
  (void)in_sizes; (void)n_in; (void)out_size; (void)ws_size;

  hipMemsetAsync(d_ws, 0, 2048, stream);   // clear counters each launch
  hipLaunchKernelGGL(lstm_k, dim3(256), dim3(NTHR), 0, stream,
                     X, Wx, Wh, b, W1, b1, lng, lnb, W2, b2, Y, CNTp, HBu, ZB);
}

// Round 9
// 3527.723 us; speedup vs baseline: 1.3367x; 1.3367x over previous
//
// LSTM Seq2Seq persistent kernel, round 9: minimized exchange chain.
// 32 groups x 8 rows x 8 WGs (co-XCD grouping g=wg&31 preserves X/L2 locality),
// per-wave flag-line barrier (no atomics, no pre-signal syncthreads),
// packed hi|lo f16 h exchange, M=8 MFMA tiles.
//
//  - 256 WGs x 256 thr, 1 WG/CU (LDS ~98KB). WG owns 128 fm cols for its
//    group's 8 rows: col(nt,lr) = (nt>>1)*256 + 32*jm + (nt&1)*16 + lr.
//  - Weights: B-frags f16 hi/lo in VGPRs (Bh/Bl[3][8], 192 VGPRs); wave wv
//    owns k-tiles {wv, wv+4, wv+8} (k-split), partials via fm_p LDS.
//  - fm = Ah*Bh + Ah*Bl + Al*Bh (fp32-grade, proven r3-r8).
//  - Exchange: h stores (sc0 sc1, packed u32) -> per-wave vmcnt(0) -> lane0
//    flag store FH[g][jm*4+wv]=t+1. Consumer: wave 0 lanes 0..7 poll the 32
//    flags (128B) until all >= tag (first check sleep-free), syncthreads,
//    all threads stage 32B each. Flag-store visibility HW-validated (r6).
//  - Decoder: same h path + z exchange via FZ flags; z/LN/relu/y head.

#include <hip/hip_runtime.h>
#include <cmath>

typedef _Float16 f16;
typedef _Float16 f16x4v __attribute__((ext_vector_type(4)));
typedef _Float16 f16x8v __attribute__((ext_vector_type(8)));
typedef float f32x4v __attribute__((ext_vector_type(4)));

#define NTHR 256

__device__ __forceinline__ float sigmoidf_(float x) { return 1.0f / (1.0f + expf(-x)); }

__device__ __forceinline__ void st_sc_u(unsigned* p, unsigned v) {
  asm volatile("global_store_dword %0, %1, off sc0 sc1" :: "v"(p), "v"(v) : "memory");
}
__device__ __forceinline__ void st_sc_f(float* p, float v) {
  asm volatile("global_store_dword %0, %1, off sc0 sc1" :: "v"(p), "v"(v) : "memory");
}

// 32B contiguous coherent load (2x dwordx4), single drain.
__device__ __forceinline__ void ld32u_sc(const unsigned* p, uint4& a, uint4& b) {
  asm volatile(
      "global_load_dwordx4 %0, %2, off sc0 sc1\n\t"
      "global_load_dwordx4 %1, %2, off offset:16 sc0 sc1\n\t"
      "s_waitcnt vmcnt(0)"
      : "=&v"(a), "=&v"(b) : "v"(p) : "memory");
}
__device__ __forceinline__ void ld32f_sc(const float* p, float4& a, float4& b) {
  asm volatile(
      "global_load_dwordx4 %0, %2, off sc0 sc1\n\t"
      "global_load_dwordx4 %1, %2, off offset:16 sc0 sc1\n\t"
      "s_waitcnt vmcnt(0)"
      : "=&v"(a), "=&v"(b) : "v"(p) : "memory");
}

// Called by ALL 64 lanes of wave 0: lanes 0..7 each watch 4 flags (16B).
__device__ __forceinline__ void poll32(const unsigned* base, unsigned want) {
  const int ln = threadIdx.x & 63;
  const unsigned* p = base + (ln & 7) * 4;
  const bool active = (ln < 8);
  unsigned guard = 0;
  for (;;) {
    uint4 f;
    asm volatile("global_load_dwordx4 %0, %1, off sc0 sc1\n\ts_waitcnt vmcnt(0)"
                 : "=v"(f) : "v"(p) : "memory");
    bool ok = !active ||
              (f.x >= want && f.y >= want && f.z >= want && f.w >= want);
    if (__all((int)ok)) return;
    if (++guard > (1u << 21)) return;   // safety valve (absmax catches corruption)
    __builtin_amdgcn_s_sleep(1);
  }
}

__device__ __forceinline__ unsigned packhl(float v) {
  f16 h = (f16)v;
  f16 lo = (f16)(v - (float)h);
  unsigned short hb, lb;
  __builtin_memcpy(&hb, &h, 2); __builtin_memcpy(&lb, &lo, 2);
  return (unsigned)hb | ((unsigned)lb << 16);
}
__device__ __forceinline__ float unpackf(unsigned u) {
  unsigned short hb = (unsigned short)(u & 0xffffu), lb = (unsigned short)(u >> 16);
  f16 h, l;
  __builtin_memcpy(&h, &hb, 2); __builtin_memcpy(&l, &lb, 2);
  return (float)h + (float)l;
}
// 4 packed u32 -> 4 hi f16 + 4 lo f16 (8B each), pure bit ops.
__device__ __forceinline__ void unpack_wr(uint4 c, f16* ph, f16* pl) {
  unsigned h01 = (c.x & 0xffffu) | (c.y << 16);
  unsigned h23 = (c.z & 0xffffu) | (c.w << 16);
  unsigned l01 = (c.x >> 16) | (c.y & 0xffff0000u);
  unsigned l23 = (c.z >> 16) | (c.w & 0xffff0000u);
  uint2 hh = {h01, h23}, ll = {l01, l23};
  *(uint2*)ph = hh; *(uint2*)pl = ll;
}
__device__ __forceinline__ void conv4_wr(float4 v, f16* ph, f16* pl) {
  f16x4v h, l;
  h[0] = (f16)v.x; h[1] = (f16)v.y; h[2] = (f16)v.z; h[3] = (f16)v.w;
  l[0] = (f16)(v.x - (float)h[0]); l[1] = (f16)(v.y - (float)h[1]);
  l[2] = (f16)(v.z - (float)h[2]); l[3] = (f16)(v.w - (float)h[3]);
  *(f16x4v*)ph = h; *(f16x4v*)pl = l;
}

__global__ __launch_bounds__(NTHR, 1) void lstm_k(
    const float* __restrict__ X,  const float* __restrict__ Wx,
    const float* __restrict__ Wh, const float* __restrict__ Bg,
    const float* __restrict__ W1, const float* __restrict__ B1,
    const float* __restrict__ LNG, const float* __restrict__ LNB,
    const float* __restrict__ W2, const float* __restrict__ B2,
    float* __restrict__ Y,
    unsigned* __restrict__ FH, unsigned* __restrict__ FZ,
    unsigned* __restrict__ HBp, float* __restrict__ ZB)
{
  // LDS ~97.6KB (forces 1 WG/CU)
  __shared__ f16   A_hi[8][392];      // [row][k]: 0..127 x(t), 128..383 h(t-1)
  __shared__ f16   A_lo[8][392];
  __shared__ float fm_p[4][128][12];  // [wave][col][row(8)+pad]
  __shared__ float hst[8][264];       // decoder f32 staging
  __shared__ float w1_lds[32][260];   // W1 slice transposed [zc][k]
  __shared__ float w2_lds[16][260];   // W2 slice transposed [yc][k]
  __shared__ float lng_lds[256], lnb_lds[256];
  __shared__ float ln_mu[8], ln_rs[8];

  const int tid = threadIdx.x;
  const int wg  = blockIdx.x;
  const int g   = wg & 31;        // group (co-XCD members: wg ≡ g mod 32)
  const int jm  = wg >> 5;        // member 0..7
  const int n0  = g * 8;          // batch rows [n0, n0+8)
  const int c0  = jm * 32;        // owned col slice (per quadrant)
  unsigned* FHg = FH + g * 32;    // 32 per-wave flags (128B line)
  unsigned* FZg = FZ + g * 32;

  const int l  = tid & 63;
  const int wv = __builtin_amdgcn_readfirstlane(tid >> 6);
  const int lr = l & 15;          // B-frag col
  const int ko = (l >> 4) * 8;    // k octet in 32-k tile
  const int ar = l & 7;           // A-frag row (M=8)

  // ---- B fragments: wave wv owns k-tiles {wv, wv+4, wv+8}, 8 n-tiles ----
  f16x8v Bh[3][8], Bl[3][8];
  #pragma unroll
  for (int ki = 0; ki < 3; ++ki) {
    const int kt = wv + 4 * ki;
    #pragma unroll
    for (int nt = 0; nt < 8; ++nt) {
      const int col = (nt >> 1) * 256 + c0 + (nt & 1) * 16 + lr;
      #pragma unroll
      for (int j = 0; j < 8; ++j) {
        int k = kt * 32 + ko + j;
        float v = (k < 128) ? Wx[k * 1024 + col] : Wh[(k - 128) * 1024 + col];
        f16 hi = (f16)v;
        Bh[ki][nt][j] = hi;
        Bl[ki][nt][j] = (f16)(v - (float)hi);
      }
    }
  }

  // ---- head weights / LN params ----
  for (int idx = tid; idx < 256 * 32; idx += NTHR) {
    int k = idx >> 5, c = idx & 31;
    w1_lds[c][k] = W1[k * 256 + c0 + c];
  }
  for (int idx = tid; idx < 256 * 16; idx += NTHR) {
    int k = idx >> 4, c = idx & 15;
    w2_lds[c][k] = W2[k * 128 + jm * 16 + c];
  }
  lng_lds[tid] = LNG[tid];
  lnb_lds[tid] = LNB[tid];

  const int gr = tid >> 5, gc = tid & 31;   // gate cell (row, col-in-slice)
  const float bias0 = Bg[      c0 + gc];
  const float bias1 = Bg[256 + c0 + gc];
  const float bias2 = Bg[512 + c0 + gc];
  const float bias3 = Bg[768 + c0 + gc];
  const float b1reg = B1[c0 + gc];
  const float b2reg = (tid < 128) ? B2[jm * 16 + (tid & 15)] : 0.0f;
  float c_reg = 0.0f;

  // ---- prologue: zero h-region, stage x(0) ----
  {
    const int row = tid >> 5, hc = (tid & 31) * 8, c4 = (tid & 31) * 4;
    f16x8v z8 = {0, 0, 0, 0, 0, 0, 0, 0};
    *(f16x8v*)&A_hi[row][128 + hc] = z8;
    *(f16x8v*)&A_lo[row][128 + hc] = z8;
    const float* xp = X + (size_t)(n0 + row) * 131072 + c4;
    conv4_wr(*(const float4*)xp, &A_hi[row][c4], &A_lo[row][c4]);
  }
  __syncthreads();

  // ================= ENCODER (t = 0..1023) =================
  for (int t = 0; t < 1024; ++t) {
    float4 xnext;
    if (t < 1023) {   // prefetch x(t+1): one float4/thread
      const float* xp = X + (size_t)(n0 + (tid >> 5)) * 131072
                          + (size_t)(t + 1) * 128 + (tid & 31) * 4;
      xnext = *(const float4*)xp;
    }

    f32x4v ac0[8], ac1[8], ac2[8];
    #pragma unroll
    for (int nt = 0; nt < 8; ++nt) {
      ac0[nt] = {0,0,0,0}; ac1[nt] = {0,0,0,0}; ac2[nt] = {0,0,0,0};
    }
    {  // x-part (independent of h(t-1)): kt = wv
      f16x8v axh = *(const f16x8v*)&A_hi[ar][wv * 32 + ko];
      f16x8v axl = *(const f16x8v*)&A_lo[ar][wv * 32 + ko];
      #pragma unroll
      for (int nt = 0; nt < 8; ++nt) {
        ac0[nt] = __builtin_amdgcn_mfma_f32_16x16x32_f16(axh, Bh[0][nt], ac0[nt], 0, 0, 0);
        ac1[nt] = __builtin_amdgcn_mfma_f32_16x16x32_f16(axh, Bl[0][nt], ac1[nt], 0, 0, 0);
        ac2[nt] = __builtin_amdgcn_mfma_f32_16x16x32_f16(axl, Bh[0][nt], ac2[nt], 0, 0, 0);
      }
    }

    if (t > 0) {  // wait h(t-1) flags, stage 8KB packed into A h-region
      if (wv == 0) poll32(FHg, (unsigned)t);
      __syncthreads();
      const int row = tid >> 5, hc = (tid & 31) * 8;
      const unsigned* hb = HBp + (size_t)((t - 1) & 1) * 65536
                               + (size_t)(n0 + row) * 256 + hc;
      uint4 a, b;
      ld32u_sc(hb, a, b);
      unpack_wr(a, &A_hi[row][128 + hc],     &A_lo[row][128 + hc]);
      unpack_wr(b, &A_hi[row][128 + hc + 4], &A_lo[row][128 + hc + 4]);
      __syncthreads();
    }

    {  // h-part: kt = wv+4, wv+8
      f16x8v ah1 = *(const f16x8v*)&A_hi[ar][(wv + 4) * 32 + ko];
      f16x8v al1 = *(const f16x8v*)&A_lo[ar][(wv + 4) * 32 + ko];
      f16x8v ah2 = *(const f16x8v*)&A_hi[ar][(wv + 8) * 32 + ko];
      f16x8v al2 = *(const f16x8v*)&A_lo[ar][(wv + 8) * 32 + ko];
      #pragma unroll
      for (int nt = 0; nt < 8; ++nt) {
        ac0[nt] = __builtin_amdgcn_mfma_f32_16x16x32_f16(ah1, Bh[1][nt], ac0[nt], 0, 0, 0);
        ac1[nt] = __builtin_amdgcn_mfma_f32_16x16x32_f16(ah1, Bl[1][nt], ac1[nt], 0, 0, 0);
        ac2[nt] = __builtin_amdgcn_mfma_f32_16x16x32_f16(al1, Bh[1][nt], ac2[nt], 0, 0, 0);
        ac0[nt] = __builtin_amdgcn_mfma_f32_16x16x32_f16(ah2, Bh[2][nt], ac0[nt], 0, 0, 0);
        ac1[nt] = __builtin_amdgcn_mfma_f32_16x16x32_f16(ah2, Bl[2][nt], ac1[nt], 0, 0, 0);
        ac2[nt] = __builtin_amdgcn_mfma_f32_16x16x32_f16(al2, Bh[2][nt], ac2[nt], 0, 0, 0);
      }
    }
    if (l < 32) {   // C rows 0..7 live in lanes 0..31
      #pragma unroll
      for (int nt = 0; nt < 8; ++nt) {
        f32x4v s = ac0[nt] + ac1[nt] + ac2[nt];
        *(f32x4v*)&fm_p[wv][nt * 16 + (l & 15)][(l >> 4) * 4] = s;
      }
    }
    __syncthreads();

    {  // gates + publish (packed) — every thread owns one (row, col) cell
      float fi = bias0, ff = bias1, fo = bias2, fg = bias3;
      #pragma unroll
      for (int ww = 0; ww < 4; ++ww) {
        fi += fm_p[ww][     gc][gr];
        ff += fm_p[ww][32 + gc][gr];
        fo += fm_p[ww][64 + gc][gr];
        fg += fm_p[ww][96 + gc][gr];
      }
      float si = sigmoidf_(fi), sf = sigmoidf_(ff), so = sigmoidf_(fo);
      float tg = tanhf(fg);
      c_reg = c_reg * sf + si * tg;
      float hv = so * tanhf(c_reg);
      st_sc_u(HBp + (size_t)(t & 1) * 65536 + (size_t)(n0 + gr) * 256 + c0 + gc,
              packhl(hv));
    }
    if (t < 1023) {   // write x(t+1) into A x-region (post-fm_p-sync: safe)
      const int row = tid >> 5, c4 = (tid & 31) * 4;
      conv4_wr(xnext, &A_hi[row][c4], &A_lo[row][c4]);
    }
    asm volatile("s_waitcnt vmcnt(0)" ::: "memory");   // per-wave drain
    if (l == 0) st_sc_u(FHg + jm * 4 + wv, (unsigned)(t + 1));
    __syncthreads();   // orders x-region write vs next iter's x-part reads
  }

  // ---- decoder prologue: stage h(1023) (parity 1) into A ----
  if (wv == 0) poll32(FHg, 1024u);
  __syncthreads();
  {
    const int row = tid >> 5, hc = (tid & 31) * 8;
    const unsigned* hb = HBp + (size_t)65536 + (size_t)(n0 + row) * 256 + hc;
    uint4 a, b;
    ld32u_sc(hb, a, b);
    unpack_wr(a, &A_hi[row][128 + hc],     &A_lo[row][128 + hc]);
    unpack_wr(b, &A_hi[row][128 + hc + 4], &A_lo[row][128 + hc + 4]);
  }
  __syncthreads();

  // ================= DECODER (s = 0..31) =================
  for (int s = 0; s < 32; ++s) {
    const int t = 1024 + s;

    f32x4v ac0[8], ac1[8], ac2[8];
    #pragma unroll
    for (int nt = 0; nt < 8; ++nt) {
      ac0[nt] = {0,0,0,0}; ac1[nt] = {0,0,0,0}; ac2[nt] = {0,0,0,0};
    }
    {  // fm = h @ Wh + b (kt = wv+4, wv+8)
      f16x8v ah1 = *(const f16x8v*)&A_hi[ar][(wv + 4) * 32 + ko];
      f16x8v al1 = *(const f16x8v*)&A_lo[ar][(wv + 4) * 32 + ko];
      f16x8v ah2 = *(const f16x8v*)&A_hi[ar][(wv + 8) * 32 + ko];
      f16x8v al2 = *(const f16x8v*)&A_lo[ar][(wv + 8) * 32 + ko];
      #pragma unroll
      for (int nt = 0; nt < 8; ++nt) {
        ac0[nt] = __builtin_amdgcn_mfma_f32_16x16x32_f16(ah1, Bh[1][nt], ac0[nt], 0, 0, 0);
        ac1[nt] = __builtin_amdgcn_mfma_f32_16x16x32_f16(ah1, Bl[1][nt], ac1[nt], 0, 0, 0);
        ac2[nt] = __builtin_amdgcn_mfma_f32_16x16x32_f16(al1, Bh[1][nt], ac2[nt], 0, 0, 0);
        ac0[nt] = __builtin_amdgcn_mfma_f32_16x16x32_f16(ah2, Bh[2][nt], ac0[nt], 0, 0, 0);
        ac1[nt] = __builtin_amdgcn_mfma_f32_16x16x32_f16(ah2, Bl[2][nt], ac1[nt], 0, 0, 0);
        ac2[nt] = __builtin_amdgcn_mfma_f32_16x16x32_f16(al2, Bh[2][nt], ac2[nt], 0, 0, 0);
      }
    }
    if (l < 32) {
      #pragma unroll
      for (int nt = 0; nt < 8; ++nt) {
        f32x4v sm = ac0[nt] + ac1[nt] + ac2[nt];
        *(f32x4v*)&fm_p[wv][nt * 16 + (l & 15)][(l >> 4) * 4] = sm;
      }
    }
    __syncthreads();

    {  // RAW gates (reference decoder: no activations on i,f,o,g)
      float fi = bias0, ff = bias1, fo = bias2, fg = bias3;
      #pragma unroll
      for (int ww = 0; ww < 4; ++ww) {
        fi += fm_p[ww][     gc][gr];
        ff += fm_p[ww][32 + gc][gr];
        fo += fm_p[ww][64 + gc][gr];
        fg += fm_p[ww][96 + gc][gr];
      }
      c_reg = c_reg * ff + fi * fg;
      float hv = fo * tanhf(c_reg);
      st_sc_u(HBp + (size_t)(t & 1) * 65536 + (size_t)(n0 + gr) * 256 + c0 + gc,
              packhl(hv));
    }
    asm volatile("s_waitcnt vmcnt(0)" ::: "memory");
    if (l == 0) st_sc_u(FHg + jm * 4 + wv, (unsigned)(t + 1));

    if (wv == 0) poll32(FHg, (unsigned)(t + 1));
    __syncthreads();
    {  // stage h(t) -> A (next fm) + hst (z input)
      const int row = tid >> 5, hc = (tid & 31) * 8;
      const unsigned* hb = HBp + (size_t)(t & 1) * 65536
                               + (size_t)(n0 + row) * 256 + hc;
      uint4 a, b;
      ld32u_sc(hb, a, b);
      unpack_wr(a, &A_hi[row][128 + hc],     &A_lo[row][128 + hc]);
      unpack_wr(b, &A_hi[row][128 + hc + 4], &A_lo[row][128 + hc + 4]);
      float4 f0 = {unpackf(a.x), unpackf(a.y), unpackf(a.z), unpackf(a.w)};
      float4 f1 = {unpackf(b.x), unpackf(b.y), unpackf(b.z), unpackf(b.w)};
      *(float4*)&hst[row][hc]     = f0;
      *(float4*)&hst[row][hc + 4] = f1;
    }
    __syncthreads();

    {  // z = h @ W1 + b1 (thread: row gr, z-col c0+gc)
      float za = b1reg;
      const float* hr = &hst[gr][0];
      const float* wr = &w1_lds[gc][0];
      #pragma unroll 4
      for (int kc = 0; kc < 64; ++kc) {
        float4 h4 = *(const float4*)(hr + kc * 4);
        float4 w4 = *(const float4*)(wr + kc * 4);
        za = fmaf(h4.x, w4.x, fmaf(h4.y, w4.y, fmaf(h4.z, w4.z, fmaf(h4.w, w4.w, za))));
      }
      st_sc_f(ZB + (size_t)(n0 + gr) * 256 + c0 + gc, za);
    }
    asm volatile("s_waitcnt vmcnt(0)" ::: "memory");
    if (l == 0) st_sc_u(FZg + jm * 4 + wv, (unsigned)(s + 1));

    if (wv == 0) poll32(FZg, (unsigned)(s + 1));
    __syncthreads();
    {  // stage z -> hst (all peers flagged => all done reading their hst)
      const int row = tid >> 5, hc = (tid & 31) * 8;
      float4 a, b;
      ld32f_sc(ZB + (size_t)(n0 + row) * 256 + hc, a, b);
      *(float4*)&hst[row][hc]     = a;
      *(float4*)&hst[row][hc + 4] = b;
    }
    __syncthreads();

    {  // LayerNorm stats: 32 threads per row
      const float* zr = &hst[gr][0];
      float s1 = 0.f, s2 = 0.f;
      #pragma unroll
      for (int u = 0; u < 2; ++u) {
        float4 v = *(const float4*)(zr + gc * 8 + u * 4);
        s1 += v.x + v.y + v.z + v.w;
        s2 += v.x * v.x + v.y * v.y + v.z * v.z + v.w * v.w;
      }
      #pragma unroll
      for (int d = 1; d < 32; d <<= 1) { s1 += __shfl_xor(s1, d); s2 += __shfl_xor(s2, d); }
      float mu = s1 * (1.0f / 256.0f);
      float var = s2 * (1.0f / 256.0f) - mu * mu;
      float rstd = rsqrtf(var + 1e-5f);
      if (gc == 0) { ln_mu[gr] = mu; ln_rs[gr] = rstd; }
    }
    __syncthreads();

    #pragma unroll
    for (int rep = 0; rep < 2; ++rep) {  // normalize + affine + relu in place
      int idx = tid + 256 * rep, r = idx >> 6, q = idx & 63;
      float mu = ln_mu[r], rs = ln_rs[r];
      float4 v = *(float4*)&hst[r][q * 4];
      int cb = q * 4;
      v.x = fmaxf(fmaf((v.x - mu) * rs, lng_lds[cb    ], lnb_lds[cb    ]), 0.f);
      v.y = fmaxf(fmaf((v.y - mu) * rs, lng_lds[cb + 1], lnb_lds[cb + 1]), 0.f);
      v.z = fmaxf(fmaf((v.z - mu) * rs, lng_lds[cb + 2], lnb_lds[cb + 2]), 0.f);
      v.w = fmaxf(fmaf((v.w - mu) * rs, lng_lds[cb + 3], lnb_lds[cb + 3]), 0.f);
      *(float4*)&hst[r][q * 4] = v;
    }
    __syncthreads();

    if (tid < 128) {  // y = relu(zn) @ W2 + b2 (row r, y-col jm*16+yc)
      int r = tid >> 4, yc = tid & 15;
      float ya = b2reg;
      const float* zr = &hst[r][0];
      const float* wr = &w2_lds[yc][0];
      #pragma unroll 4
      for (int kc = 0; kc < 64; ++kc) {
        float4 z4 = *(const float4*)(zr + kc * 4);
        float4 w4 = *(const float4*)(wr + kc * 4);
        ya = fmaf(z4.x, w4.x, fmaf(z4.y, w4.y, fmaf(z4.z, w4.z, fmaf(z4.w, w4.w, ya))));
      }
      Y[(size_t)(n0 + r) * 4096 + (size_t)s * 128 + jm * 16 + yc] = ya;
    }
    __syncthreads();
  }
}

extern "C" void kernel_launch(void* const* d_in, const int* in_sizes, int n_in,
                              void* d_out, int out_size, void* d_ws, size_t ws_size,
                              hipStream_t stream) {
  const float* X   = (const float*)d_in[0];
  const float* Wx  = (const float*)d_in[1];
  const float* Wh  = (const float*)d_in[2];
  const float* b   = (const float*)d_in[3];
  const float* W1  = (const float*)d_in[4];
  const float* b1  = (const float*)d_in[5];
  const float* lng = (const float*)d_in[6];
  const float* lnb = (const float*)d_in[7];
  const float* W2  = (const float*)d_in[8];
  const float* b2  = (const float*)d_in[9];
  float* Y = (float*)d_out;

  // ws layout (bytes):
  //  [0,4096)       FH   h flags  [32 groups][32] u32 (128B/group)
  //  [4096,8192)    FZ   z flags  [32 groups][32] u32
  //  [8192,+512KB)  HBp  packed h double buffer [2][256][256] u32
  //  then 256KB     ZB   z buffer [256][256] f32
  unsigned* FH  = (unsigned*)d_ws;
  unsigned* FZ  = (unsigned*)((char*)d_ws + 4096);
  unsigned* HBp = (unsigned*)((char*)d_ws + 8192);
  float*    ZB  = (float*)((char*)d_ws + 8192 + 524288);
  (void)in_sizes; (void)n_in; (void)out_size; (void)ws_size;

  hipMemsetAsync(d_ws, 0, 8192, stream);   // clear flags each launch
  hipLaunchKernelGGL(lstm_k, dim3(256), dim3(NTHR), 0, stream,
                     X, Wx, Wh, b, W1, b1, lng, lnb, W2, b2, Y, FH, FZ, HBp, ZB);
}

// Round 10
// 2884.862 us; speedup vs baseline: 1.6346x; 1.2228x over previous
//
// LSTM Seq2Seq persistent kernel, round 10: r3 skeleton + three surgical cuts.
//  (1) wave-private gates: B columns quadrant-interleaved (wave wv owns h-cols
//      [16jm+4wv, +4) x all 4 gate quadrants) -> gate combine is wave-local LDS
//      (fm_w), no cross-wave reduce, no syncthreads between fm and gates.
//  (2) fast transcendentals: sigmoid/tanh via v_exp_f32 + v_rcp_f32.
//  (3) h exchanged as packed (f16 hi | f16 lo) u32; consumer unpack = bit-ops.
//  Everything else r3-proven: 16 groups x 16 WGs (co-XCD), atomic-counter
//  barrier (drain->sync->atomic; single poller + s_sleep), coalesced staging,
//  f16 hi/lo MFMA (3 chains), decoder z/LN/relu/y head.

#include <hip/hip_runtime.h>
#include <cmath>

typedef _Float16 f16;
typedef _Float16 f16x8v __attribute__((ext_vector_type(8)));
typedef float f32x4v __attribute__((ext_vector_type(4)));

#define NTHR 256
#define WPG  16

// ---- fast transcendentals (v_exp_f32 / v_rcp_f32) ----
__device__ __forceinline__ float fexp2_(float x) {
#if __has_builtin(__builtin_amdgcn_exp2f)
  return __builtin_amdgcn_exp2f(x);
#else
  return exp2f(x);
#endif
}
__device__ __forceinline__ float frcp_(float x) {
#if __has_builtin(__builtin_amdgcn_rcpf)
  return __builtin_amdgcn_rcpf(x);
#else
  return 1.0f / x;
#endif
}
__device__ __forceinline__ float fsigmoid(float x) {
  float xc = fminf(fmaxf(x, -60.f), 60.f);
  return frcp_(1.f + fexp2_(xc * -1.44269504f));
}
__device__ __forceinline__ float ftanh_(float x) {
  float xc = fminf(fmaxf(x, -15.f), 15.f);
  float e = fexp2_(xc * 2.88539008f);     // e^(2x)
  return (e - 1.f) * frcp_(e + 1.f);
}

__device__ __forceinline__ void st_sc_u(unsigned* p, unsigned v) {
  asm volatile("global_store_dword %0, %1, off sc0 sc1" :: "v"(p), "v"(v) : "memory");
}
__device__ __forceinline__ void st_sc_f(float* p, float v) {
  asm volatile("global_store_dword %0, %1, off sc0 sc1" :: "v"(p), "v"(v) : "memory");
}

// 64B contiguous coherent load, single drain.
__device__ __forceinline__ void ld64u_sc(const unsigned* p, uint4& a, uint4& b,
                                         uint4& c, uint4& d) {
  asm volatile(
      "global_load_dwordx4 %0, %4, off sc0 sc1\n\t"
      "global_load_dwordx4 %1, %4, off offset:16 sc0 sc1\n\t"
      "global_load_dwordx4 %2, %4, off offset:32 sc0 sc1\n\t"
      "global_load_dwordx4 %3, %4, off offset:48 sc0 sc1\n\t"
      "s_waitcnt vmcnt(0)"
      : "=&v"(a), "=&v"(b), "=&v"(c), "=&v"(d) : "v"(p) : "memory");
}
// 4 coherent 16B loads, 4KB apart (r3 pattern), single drain.
__device__ __forceinline__ void ld4f_sc(const float* p, float4& a, float4& b,
                                        float4& c, float4& d) {
  asm volatile(
      "global_load_dwordx4 %0, %4, off sc0 sc1\n\t"
      "global_load_dwordx4 %1, %5, off sc0 sc1\n\t"
      "global_load_dwordx4 %2, %6, off sc0 sc1\n\t"
      "global_load_dwordx4 %3, %7, off sc0 sc1\n\t"
      "s_waitcnt vmcnt(0)"
      : "=&v"(a), "=&v"(b), "=&v"(c), "=&v"(d)
      : "v"(p), "v"(p + 1024), "v"(p + 2048), "v"(p + 3072) : "memory");
}

__device__ __forceinline__ void arrive_bar(unsigned* cg) {
  asm volatile("s_waitcnt vmcnt(0)" ::: "memory");   // drain sc1 stores
  __syncthreads();
  if (threadIdx.x == 0)
    (void)__hip_atomic_fetch_add(cg, 1u, __ATOMIC_RELAXED, __HIP_MEMORY_SCOPE_AGENT);
}
__device__ __forceinline__ void wait_bar(unsigned* cg, unsigned target) {
  if (threadIdx.x == 0) {
    unsigned guard = 0;
    while (__hip_atomic_load(cg, __ATOMIC_RELAXED, __HIP_MEMORY_SCOPE_AGENT) < target) {
      __builtin_amdgcn_s_sleep(1);
      if (++guard > (1u << 22)) break;   // safety valve
    }
  }
  __syncthreads();
}

__device__ __forceinline__ unsigned packhl(float v) {
  f16 h = (f16)v;
  f16 lo = (f16)(v - (float)h);
  unsigned short hb, lb;
  __builtin_memcpy(&hb, &h, 2); __builtin_memcpy(&lb, &lo, 2);
  return (unsigned)hb | ((unsigned)lb << 16);
}
__device__ __forceinline__ float unpackf(unsigned u) {
  unsigned short hb = (unsigned short)(u & 0xffffu), lb = (unsigned short)(u >> 16);
  f16 h, l;
  __builtin_memcpy(&h, &hb, 2); __builtin_memcpy(&l, &lb, 2);
  return (float)h + (float)l;
}
// 4 packed u32 -> 4 hi f16 (8B) + 4 lo f16 (8B), pure bit-ops.
__device__ __forceinline__ void unpack_wr(uint4 c, f16* ph, f16* pl) {
  unsigned h01 = (c.x & 0xffffu) | (c.y << 16);
  unsigned h23 = (c.z & 0xffffu) | (c.w << 16);
  unsigned l01 = (c.x >> 16) | (c.y & 0xffff0000u);
  unsigned l23 = (c.z >> 16) | (c.w & 0xffff0000u);
  uint2 hh = {h01, h23}, ll = {l01, l23};
  *(uint2*)ph = hh; *(uint2*)pl = ll;
}
__device__ __forceinline__ void conv8_wr(float4 a, float4 b, f16* ph, f16* pl) {
  f16x8v h, l;
  h[0]=(f16)a.x; h[1]=(f16)a.y; h[2]=(f16)a.z; h[3]=(f16)a.w;
  h[4]=(f16)b.x; h[5]=(f16)b.y; h[6]=(f16)b.z; h[7]=(f16)b.w;
  l[0]=(f16)(a.x-(float)h[0]); l[1]=(f16)(a.y-(float)h[1]);
  l[2]=(f16)(a.z-(float)h[2]); l[3]=(f16)(a.w-(float)h[3]);
  l[4]=(f16)(b.x-(float)h[4]); l[5]=(f16)(b.y-(float)h[5]);
  l[6]=(f16)(b.z-(float)h[6]); l[7]=(f16)(b.w-(float)h[7]);
  *(f16x8v*)ph = h; *(f16x8v*)pl = l;
}

__global__ __launch_bounds__(NTHR, 1) void lstm_k(
    const float* __restrict__ X,  const float* __restrict__ Wx,
    const float* __restrict__ Wh, const float* __restrict__ Bg,
    const float* __restrict__ W1, const float* __restrict__ B1,
    const float* __restrict__ LNG, const float* __restrict__ LNB,
    const float* __restrict__ W2, const float* __restrict__ B2,
    float* __restrict__ Y, unsigned* __restrict__ CNT,
    unsigned* __restrict__ HBp, float* __restrict__ ZB)
{
  // LDS ~73KB
  __shared__ f16   A_hi[16][392];     // [row][k]: 0..127 x(t), 128..383 h(t-1)
  __shared__ f16   A_lo[16][392];
  __shared__ float fm_w[4][16][20];   // wave-PRIVATE fm tile [wv][col16][row16+pad]
  __shared__ float hst[16][260];      // decoder f32 staging
  __shared__ float w1_lds[16][268];   // W1 slice transposed [zc][k]
  __shared__ float w2_lds[8][268];    // W2 slice transposed [yc][k]
  __shared__ float lng_lds[256], lnb_lds[256];
  __shared__ float ln_mu[16], ln_rs[16];

  const int tid = threadIdx.x;
  const int wg  = blockIdx.x;
  const int g   = wg & 15;        // group (members co-XCD: wg ≡ g mod 16)
  const int jm  = wg >> 4;        // member 0..15; owns h-cols [16jm, 16jm+16)
  const int n0  = g * 16;
  const int k0  = jm * 16;
  unsigned* cg  = CNT + g * 32;   // 128B-spaced per-group counter

  const int l     = tid & 63;
  const int wv    = __builtin_amdgcn_readfirstlane(tid >> 6);
  const int arow  = l & 15;           // A-frag row
  const int krow0 = (l >> 4) * 8;     // k octet within 32-k tile

  // Wave wv owns h-cols [k0+4wv, k0+4wv+4) x 4 quadrants (16 fm cols).
  // B tile col (l&15) = 4*q + hc  ->  global col = q*256 + k0 + 4wv + hc.
  const int qq = (l >> 2) & 3;        // quadrant of this lane's B column
  const int hc = l & 3;               // h-col within wave's 4
  const int ch = k0 + 4 * wv + hc;    // global h column

  // ---- B fragments (quadrant-interleaved cols), f16 hi/lo, 12 k-tiles ----
  f16x8v Bh[12], Bl[12];
  {
    const int bcol = qq * 256 + ch;
    #pragma unroll
    for (int kt = 0; kt < 12; ++kt) {
      #pragma unroll
      for (int j = 0; j < 8; ++j) {
        int k = kt * 32 + krow0 + j;
        float v = (kt < 4) ? Wx[k * 1024 + bcol] : Wh[(k - 128) * 1024 + bcol];
        f16 hi = (f16)v;
        Bh[kt][j] = hi;
        Bl[kt][j] = (f16)(v - (float)hi);
      }
    }
  }

  // ---- head weights / LN params ----
  for (int idx = tid; idx < 256 * 16; idx += NTHR) {
    int k = idx >> 4, cc = idx & 15;
    w1_lds[cc][k] = W1[k * 256 + k0 + cc];
  }
  for (int idx = tid; idx < 256 * 8; idx += NTHR) {
    int k = idx >> 3, cc = idx & 7;
    w2_lds[cc][k] = W2[k * 128 + jm * 8 + cc];
  }
  lng_lds[tid] = LNG[tid];
  lnb_lds[tid] = LNB[tid];

  // per-lane gate biases (all 4 quadrants of column ch)
  const float biasI = Bg[        ch];
  const float biasF = Bg[256   + ch];
  const float biasO = Bg[512   + ch];
  const float biasG = Bg[768   + ch];
  const int   myrow = (l >> 4) * 4 + qq;   // owned cell row (bijective over wave)
  float c_reg = 0.0f;                      // cell state (myrow, ch)

  const int gr = tid >> 4, gk = tid & 15;  // decoder z/LN roles (r3)
  const float b1reg = B1[k0 + gk];
  const float b2reg = (tid < 128) ? B2[jm * 8 + (tid & 7)] : 0.0f;

  // ---- prologue: x(0) into A, h region zeroed ----
  {
    const float* xp = X + (size_t)(n0 + (tid >> 4)) * 131072 + (size_t)(tid & 15) * 8;
    conv8_wr(*(const float4*)xp, *(const float4*)(xp + 4),
             &A_hi[tid >> 4][(tid & 15) * 8], &A_lo[tid >> 4][(tid & 15) * 8]);
    f16x8v z8 = {0,0,0,0,0,0,0,0};
    *(f16x8v*)&A_hi[tid >> 4][128 + (tid & 15) * 16]     = z8;
    *(f16x8v*)&A_hi[tid >> 4][128 + (tid & 15) * 16 + 8] = z8;
    *(f16x8v*)&A_lo[tid >> 4][128 + (tid & 15) * 16]     = z8;
    *(f16x8v*)&A_lo[tid >> 4][128 + (tid & 15) * 16 + 8] = z8;
  }
  __syncthreads();

  // stage packed h (16 x 256 u32) into A h-region; thread = 64B contiguous
  auto stage_hA = [&](const unsigned* hb) {
    const int row = tid >> 4, cb = (tid & 15) * 16;
    uint4 c0, c1, c2, c3;
    ld64u_sc(hb + (size_t)row * 256 + cb, c0, c1, c2, c3);
    unpack_wr(c0, &A_hi[row][128 + cb],      &A_lo[row][128 + cb]);
    unpack_wr(c1, &A_hi[row][128 + cb + 4],  &A_lo[row][128 + cb + 4]);
    unpack_wr(c2, &A_hi[row][128 + cb + 8],  &A_lo[row][128 + cb + 8]);
    unpack_wr(c3, &A_hi[row][128 + cb + 12], &A_lo[row][128 + cb + 12]);
  };

  // ================= ENCODER (t = 0..1023) =================
  for (int t = 0; t < 1024; ++t) {
    float4 xa, xb;
    if (t < 1023) {   // prefetch x(t+1) (plain cached loads)
      const float* xp = X + (size_t)(n0 + (tid >> 4)) * 131072
                          + (size_t)(t + 1) * 128 + (size_t)(tid & 15) * 8;
      xa = *(const float4*)xp;
      xb = *(const float4*)(xp + 4);
    }

    // ---- x-part: kt 0..3 (independent of h(t-1)) ----
    f32x4v ac0 = {0,0,0,0}, ac1 = {0,0,0,0}, ac2 = {0,0,0,0};
    {
      f16x8v xh[4], xl[4];
      const f16* pah = &A_hi[arow][krow0];
      const f16* pal = &A_lo[arow][krow0];
      #pragma unroll
      for (int kt = 0; kt < 4; ++kt) {
        xh[kt] = *(const f16x8v*)(pah + kt * 32);
        xl[kt] = *(const f16x8v*)(pal + kt * 32);
      }
      #pragma unroll
      for (int kt = 0; kt < 4; ++kt) {
        ac0 = __builtin_amdgcn_mfma_f32_16x16x32_f16(xh[kt], Bh[kt], ac0, 0, 0, 0);
        ac1 = __builtin_amdgcn_mfma_f32_16x16x32_f16(xh[kt], Bl[kt], ac1, 0, 0, 0);
        ac2 = __builtin_amdgcn_mfma_f32_16x16x32_f16(xl[kt], Bh[kt], ac2, 0, 0, 0);
      }
    }

    // ---- wait h(t-1), stage packed into A ----
    if (t > 0) {
      wait_bar(cg, (unsigned)(WPG * t));
      stage_hA(HBp + (size_t)((t - 1) & 1) * 65536 + (size_t)n0 * 256);
      __syncthreads();
    }

    // ---- h-part: kt 4..11 ----
    {
      f16x8v hh[8], hl[8];
      const f16* pah = &A_hi[arow][128 + krow0];
      const f16* pal = &A_lo[arow][128 + krow0];
      #pragma unroll
      for (int kt = 0; kt < 8; ++kt) {
        hh[kt] = *(const f16x8v*)(pah + kt * 32);
        hl[kt] = *(const f16x8v*)(pal + kt * 32);
      }
      #pragma unroll
      for (int kt = 0; kt < 8; ++kt) {
        ac0 = __builtin_amdgcn_mfma_f32_16x16x32_f16(hh[kt], Bh[kt + 4], ac0, 0, 0, 0);
        ac1 = __builtin_amdgcn_mfma_f32_16x16x32_f16(hh[kt], Bl[kt + 4], ac1, 0, 0, 0);
        ac2 = __builtin_amdgcn_mfma_f32_16x16x32_f16(hl[kt], Bh[kt + 4], ac2, 0, 0, 0);
      }
    }

    // ---- wave-private gates (no cross-wave sync) ----
    {
      f32x4v ac = ac0 + ac1 + ac2;
      *(f32x4v*)&fm_w[wv][l & 15][(l >> 4) * 4] = ac;   // col=l&15, rows 4(l>>4)+
      // same-wave LDS: compiler orders via lgkmcnt; no barrier needed
      float fi = fm_w[wv][     hc][myrow] + biasI;
      float ff = fm_w[wv][ 4 + hc][myrow] + biasF;
      float fo = fm_w[wv][ 8 + hc][myrow] + biasO;
      float fg = fm_w[wv][12 + hc][myrow] + biasG;
      float si = fsigmoid(fi), sf = fsigmoid(ff), so = fsigmoid(fo);
      float tg = ftanh_(fg);
      c_reg = c_reg * sf + si * tg;
      float hv = so * ftanh_(c_reg);
      st_sc_u(HBp + (size_t)(t & 1) * 65536 + (size_t)(n0 + myrow) * 256 + ch,
              packhl(hv));
    }

    if (t == 0) __syncthreads();   // protect x(0) frag reads (no wait_bar at t=0)
    if (t < 1023)
      conv8_wr(xa, xb, &A_hi[tid >> 4][(tid & 15) * 8], &A_lo[tid >> 4][(tid & 15) * 8]);
    arrive_bar(cg);   // drain + sync + atomic
  }

  // ---- decoder prologue: stage h(1023) (parity 1) ----
  wait_bar(cg, (unsigned)(WPG * 1024));
  stage_hA(HBp + (size_t)65536 + (size_t)n0 * 256);
  __syncthreads();
  unsigned arr = 1024;

  // ================= DECODER (s = 0..31) =================
  for (int s = 0; s < 32; ++s) {
    const int t = 1024 + s;

    // fm = h @ Wh + b  (kt 4..11)
    f32x4v ac0 = {0,0,0,0}, ac1 = {0,0,0,0}, ac2 = {0,0,0,0};
    {
      f16x8v hh[8], hl[8];
      const f16* pah = &A_hi[arow][128 + krow0];
      const f16* pal = &A_lo[arow][128 + krow0];
      #pragma unroll
      for (int kt = 0; kt < 8; ++kt) {
        hh[kt] = *(const f16x8v*)(pah + kt * 32);
        hl[kt] = *(const f16x8v*)(pal + kt * 32);
      }
      #pragma unroll
      for (int kt = 0; kt < 8; ++kt) {
        ac0 = __builtin_amdgcn_mfma_f32_16x16x32_f16(hh[kt], Bh[kt + 4], ac0, 0, 0, 0);
        ac1 = __builtin_amdgcn_mfma_f32_16x16x32_f16(hh[kt], Bl[kt + 4], ac1, 0, 0, 0);
        ac2 = __builtin_amdgcn_mfma_f32_16x16x32_f16(hl[kt], Bh[kt + 4], ac2, 0, 0, 0);
      }
    }
    {  // wave-private RAW gates (reference decoder: no activations on i,f,o,g)
      f32x4v ac = ac0 + ac1 + ac2;
      *(f32x4v*)&fm_w[wv][l & 15][(l >> 4) * 4] = ac;
      float fi = fm_w[wv][     hc][myrow] + biasI;
      float ff = fm_w[wv][ 4 + hc][myrow] + biasF;
      float fo = fm_w[wv][ 8 + hc][myrow] + biasO;
      float fg = fm_w[wv][12 + hc][myrow] + biasG;
      c_reg = c_reg * ff + fi * fg;
      float hv = fo * ftanh_(c_reg);
      st_sc_u(HBp + (size_t)(t & 1) * 65536 + (size_t)(n0 + myrow) * 256 + ch,
              packhl(hv));
    }
    arrive_bar(cg); ++arr;
    wait_bar(cg, WPG * arr);

    {  // stage h(t): packed -> A (next fm) AND f32 -> hst (z input)
      const int row = tid >> 4, cb = (tid & 15) * 16;
      const unsigned* hb = HBp + (size_t)(t & 1) * 65536 + (size_t)n0 * 256
                               + (size_t)row * 256 + cb;
      uint4 c0, c1, c2, c3;
      ld64u_sc(hb, c0, c1, c2, c3);
      unpack_wr(c0, &A_hi[row][128 + cb],      &A_lo[row][128 + cb]);
      unpack_wr(c1, &A_hi[row][128 + cb + 4],  &A_lo[row][128 + cb + 4]);
      unpack_wr(c2, &A_hi[row][128 + cb + 8],  &A_lo[row][128 + cb + 8]);
      unpack_wr(c3, &A_hi[row][128 + cb + 12], &A_lo[row][128 + cb + 12]);
      float4 f0 = {unpackf(c0.x), unpackf(c0.y), unpackf(c0.z), unpackf(c0.w)};
      float4 f1 = {unpackf(c1.x), unpackf(c1.y), unpackf(c1.z), unpackf(c1.w)};
      float4 f2 = {unpackf(c2.x), unpackf(c2.y), unpackf(c2.z), unpackf(c2.w)};
      float4 f3 = {unpackf(c3.x), unpackf(c3.y), unpackf(c3.z), unpackf(c3.w)};
      *(float4*)&hst[row][cb]      = f0;
      *(float4*)&hst[row][cb + 4]  = f1;
      *(float4*)&hst[row][cb + 8]  = f2;
      *(float4*)&hst[row][cb + 12] = f3;
    }
    __syncthreads();

    {  // z[gr][k0+gk] = h(t)[gr] . W1[:,k0+gk] + b1
      float za = b1reg;
      const float* hr = &hst[gr][0];
      const float* wr = &w1_lds[gk][0];
      #pragma unroll 4
      for (int kc = 0; kc < 64; ++kc) {
        float4 h4 = *(const float4*)(hr + kc * 4);
        float4 w4 = *(const float4*)(wr + kc * 4);
        za = fmaf(h4.x, w4.x, fmaf(h4.y, w4.y, fmaf(h4.z, w4.z, fmaf(h4.w, w4.w, za))));
      }
      st_sc_f(ZB + (size_t)(n0 + gr) * 256 + k0 + gk, za);
    }
    arrive_bar(cg); ++arr;
    wait_bar(cg, WPG * arr);

    {  // stage z -> hst (r3 pattern)
      const float* zs = ZB + (size_t)n0 * 256 + (size_t)tid * 4;
      float4 v0, v1, v2, v3;
      ld4f_sc(zs, v0, v1, v2, v3);
      const int w0 = tid >> 6, cl = (tid & 63) * 4;
      *(float4*)&hst[w0     ][cl] = v0;
      *(float4*)&hst[w0 + 4 ][cl] = v1;
      *(float4*)&hst[w0 + 8 ][cl] = v2;
      *(float4*)&hst[w0 + 12][cl] = v3;
    }
    __syncthreads();

    {  // LayerNorm stats
      const float* zr = &hst[gr][0];
      float s1 = 0.f, s2 = 0.f;
      #pragma unroll
      for (int u = 0; u < 16; ++u) { float v = zr[gk * 16 + u]; s1 += v; s2 += v * v; }
      #pragma unroll
      for (int d = 1; d < 16; d <<= 1) { s1 += __shfl_xor(s1, d); s2 += __shfl_xor(s2, d); }
      float mu = s1 * (1.0f / 256.0f);
      float var = s2 * (1.0f / 256.0f) - mu * mu;
      float rstd = rsqrtf(var + 1e-5f);
      if (gk == 0) { ln_mu[gr] = mu; ln_rs[gr] = rstd; }
    }
    __syncthreads();

    #pragma unroll
    for (int rep = 0; rep < 4; ++rep) {  // normalize + affine + relu in place
      int f = tid + 256 * rep, r = f >> 6, kq = f & 63;
      float mu = ln_mu[r], rs = ln_rs[r];
      float4 v = *(float4*)&hst[r][kq * 4];
      int cb = kq * 4;
      v.x = fmaxf(fmaf((v.x - mu) * rs, lng_lds[cb    ], lnb_lds[cb    ]), 0.f);
      v.y = fmaxf(fmaf((v.y - mu) * rs, lng_lds[cb + 1], lnb_lds[cb + 1]), 0.f);
      v.z = fmaxf(fmaf((v.z - mu) * rs, lng_lds[cb + 2], lnb_lds[cb + 2]), 0.f);
      v.w = fmaxf(fmaf((v.w - mu) * rs, lng_lds[cb + 3], lnb_lds[cb + 3]), 0.f);
      *(float4*)&hst[r][kq * 4] = v;
    }
    __syncthreads();

    if (tid < 128) {  // y[r][jm*8+yc] = relu(zn)[r] . W2[:,jm*8+yc] + b2
      int r = tid >> 3, yc = tid & 7;
      float ya = b2reg;
      const float* zr = &hst[r][0];
      const float* wr = &w2_lds[yc][0];
      #pragma unroll 4
      for (int kc = 0; kc < 64; ++kc) {
        float4 z4 = *(const float4*)(zr + kc * 4);
        float4 w4 = *(const float4*)(wr + kc * 4);
        ya = fmaf(z4.x, w4.x, fmaf(z4.y, w4.y, fmaf(z4.z, w4.z, fmaf(z4.w, w4.w, ya))));
      }
      Y[(size_t)(n0 + r) * 4096 + (size_t)s * 128 + jm * 8 + yc] = ya;
    }
    __syncthreads();   // hst/A safe before next iteration
  }
}

extern "C" void kernel_launch(void* const* d_in, const int* in_sizes, int n_in,
                              void* d_out, int out_size, void* d_ws, size_t ws_size,
                              hipStream_t stream) {
  const float* X   = (const float*)d_in[0];
  const float* Wx  = (const float*)d_in[1];
  const float* Wh  = (const float*)d_in[2];
  const float* b   = (const float*)d_in[3];
  const float* W1  = (const float*)d_in[4];
  const float* b1  = (const float*)d_in[5];
  const float* lng = (const float*)d_in[6];
  const float* lnb = (const float*)d_in[7];
  const float* W2  = (const float*)d_in[8];
  const float* b2  = (const float*)d_in[9];
  float* Y = (float*)d_out;

  // ws layout (bytes):
  //  [0,2048)        CNT  per-group counters (16 x 128B)
  //  [4096,+512KB)   HBp  packed h double buffer [2][256][256] u32
  //  then 256KB      ZB   z buffer [256][256] f32
  unsigned* CNTp = (unsigned*)d_ws;
  unsigned* HBp  = (unsigned*)((char*)d_ws + 4096);
  float*    ZB   = (float*)((char*)d_ws + 4096 + 524288);
  (void)in_sizes; (void)n_in; (void)out_size; (void)ws_size;

  hipMemsetAsync(d_ws, 0, 2048, stream);   // clear counters each launch
  hipLaunchKernelGGL(lstm_k, dim3(256), dim3(NTHR), 0, stream,
                     X, Wx, Wh, b, W1, b1, lng, lnb, W2, b2, Y, CNTp, HBp, ZB);
}